// Round 17
// baseline (202.690 us; speedup 1.0000x reference)
//
#include <hip/hip_runtime.h>
#include <hip/hip_cooperative_groups.h>
#include <cstdint>
#include <cstddef>

namespace cg = cooperative_groups;

#define DEVINL __device__ __forceinline__

static constexpr int Bdim = 2, Ldim = 32, Cdim = 128, Hdim = 32, Wdim = 32;
static constexpr int HW  = Hdim * Wdim;         // 1024
static constexpr int CHW = Cdim * HW;           // 131072
static constexpr size_t OUT0_ELEMS = (size_t)Bdim * Ldim * CHW;  // 8388608
static constexpr size_t OUT1_CPLX  = (size_t)Bdim * CHW;         // 262144 complex elems

typedef __attribute__((ext_vector_type(8))) short short8v;   // 8 bf16 (4 VGPR)
typedef __attribute__((ext_vector_type(4))) float f32x4;     // MFMA C/D

DEVINL int bitrev5(int v) {
    return ((v&1)<<4) | ((v&2)<<2) | (v&4) | ((v&8)>>2) | ((v&16)>>4);
}
DEVINL unsigned short f2bf(float v) {               // RNE f32 -> bf16 bits
    unsigned u = __float_as_uint(v);
    return (unsigned short)((u + 0x7FFFu + ((u >> 16) & 1u)) >> 16);
}
DEVINL void bfsplit(float v, short& hi, short& lo) {
    unsigned short hb = f2bf(v);
    hi = (short)hb;
    float hf = __uint_as_float(((unsigned)hb) << 16);
    lo = (short)f2bf(v - hf);
}
DEVINL unsigned pack2bf(float2 v) {
    return (unsigned)f2bf(v.x) | ((unsigned)f2bf(v.y) << 16);
}
DEVINL float2 unpack2bf(unsigned u) {
    return make_float2(__uint_as_float(u << 16), __uint_as_float(u & 0xFFFF0000u));
}

// ================= 32-point radix-2 DIT FFT, fully in registers =================
template<int INV>
DEVINL void fft32_reg(float2 v[32]) {
    constexpr float TC[16] = { 1.0f, 0.980785280f, 0.923879533f, 0.831469612f,
                               0.707106781f, 0.555570233f, 0.382683432f, 0.195090322f,
                               0.0f, -0.195090322f, -0.382683432f, -0.555570233f,
                              -0.707106781f, -0.831469612f, -0.923879533f, -0.980785280f };
    constexpr float TS[16] = { 0.0f, -0.195090322f, -0.382683432f, -0.555570233f,
                              -0.707106781f, -0.831469612f, -0.923879533f, -0.980785280f,
                              -1.0f, -0.980785280f, -0.923879533f, -0.831469612f,
                              -0.707106781f, -0.555570233f, -0.382683432f, -0.195090322f };
#pragma unroll
    for (int st = 0; st < 5; ++st) {
        const int half = 1 << st;
#pragma unroll
        for (int bf = 0; bf < 16; ++bf) {
            const int g = bf >> st;
            const int j = bf & (half - 1);
            const int i0 = (g << (st+1)) + j;
            const float wr = TC[j << (4-st)];
            const float wi = INV ? -TS[j << (4-st)] : TS[j << (4-st)];
            float2 a0 = v[i0], a1 = v[i0+half];
            float tr = wr*a1.x - wi*a1.y;
            float ti = wr*a1.y + wi*a1.x;
            v[i0]      = make_float2(a0.x+tr, a0.y+ti);
            v[i0+half] = make_float2(a0.x-tr, a0.y-ti);
        }
    }
}

// ======================= A-pack + gamma table (verified r16) ==========
__global__ __launch_bounds__(256) void pack_w_kernel(
    const float* __restrict__ Wb_re, const float* __restrict__ Wb_im,
    const float* __restrict__ Wc_re, const float* __restrict__ Wc_im,
    const float* __restrict__ pl,
    short* __restrict__ Apack, float* __restrict__ gamma_tab)
{
    const int gid = blockIdx.x*256 + threadIdx.x;    // 0..12287
    if (gid < 4096) {                                 // Wb re/im, K=128
        const int a2   = gid >> 11;
        const int rem  = gid & 2047;
        const int f    = rem >> 6;
        const int lane = rem & 63;
        const int m  = f >> 2, kc = f & 3;
        const int row = m*16 + (lane & 15);
        const int kbase = kc*32 + ((lane >> 4) << 3);
        short8v hi8, lo8;
#pragma unroll
        for (int j = 0; j < 8; ++j) {
            const int c = kbase + j;
            const float v = a2 ? Wb_im[row*Cdim + c] : Wb_re[row*Cdim + c];
            short h, l; bfsplit(v, h, l);
            hi8[j] = h; lo8[j] = l;
        }
        const size_t off = (size_t)(f*64 + lane)*8;
        const size_t base = (size_t)a2 * 32768;
        *reinterpret_cast<short8v*>(Apack + base + off)         = hi8;
        *reinterpret_cast<short8v*>(Apack + base + 16384 + off) = lo8;
    } else if (gid < 8192) {                          // Wc, K=256
        const int rem  = gid - 4096;
        const int f    = rem >> 6;
        const int lane = rem & 63;
        const int m  = f >> 3, kc = f & 7;
        const int row = m*16 + (lane & 15);
        const int kbase = kc*32 + ((lane >> 4) << 3);
        short8v hi8, lo8;
#pragma unroll
        for (int j = 0; j < 8; ++j) {
            const int k = kbase + j;
            const int half = k >> 7;
            const int c = k & 127;
            const float v = half ? -Wc_im[row*Cdim + c] : Wc_re[row*Cdim + c];
            short h, l; bfsplit(v, h, l);
            hi8[j] = h; lo8[j] = l;
        }
        const size_t off = (size_t)(f*64 + lane)*8;
        *reinterpret_cast<short8v*>(Apack + 65536 + off)         = hi8;
        *reinterpret_cast<short8v*>(Apack + 65536 + 32768 + off) = lo8;
    } else {                                          // gamma table
        const int idx = gid - 8192;
        const int c = idx >> 5, hf = idx & 31;
        gamma_tab[idx] = expf(pl[(2*Cdim + c)*Hdim + hf]);
    }
}

// ======================= spatial Wb-mix (verified r16) ================
__global__ __launch_bounds__(256) void mix0_spatial_kernel(
    const float* __restrict__ x,
    unsigned* __restrict__ Sout,
    const short* __restrict__ Apack)
{
    __shared__ short Bs[4][4][64][8];    // 16 KB
    const int bx = blockIdx.x;           // 64 bl * 16 tt
    const int bl = bx >> 4, tt = bx & 15;
    const int t = threadIdx.x;
    const int wv = t >> 6, lane = t & 63;

    const float* src = x + (size_t)bl*CHW + tt*64;
#pragma unroll
    for (int g = 0; g < 4; ++g) {
        const int id = g*256 + t;
        const int hw = id & 63;
        const int co = id >> 6;
        const int kc = co >> 2;
        const int ln = (co & 3)*16 + (hw & 15);
        const int nt4 = hw >> 4;
        short8v b8;
#pragma unroll
        for (int j = 0; j < 8; ++j)
            b8[j] = (short)f2bf(src[(size_t)(co*8 + j)*HW + hw]);
        *reinterpret_cast<short8v*>(&Bs[kc][nt4][ln][0]) = b8;
    }
    __syncthreads();

    f32x4 accRe[2][4];
    f32x4 accIm[2][4];
#pragma unroll
    for (int mi = 0; mi < 2; ++mi)
#pragma unroll
        for (int nt = 0; nt < 4; ++nt) {
            accRe[mi][nt] = (f32x4)(0.0f);
            accIm[mi][nt] = (f32x4)(0.0f);
        }

    const short* Are_hi = Apack;
    const short* Are_lo = Apack + 16384;
    const short* Aim_hi = Apack + 32768;
    const short* Aim_lo = Apack + 49152;

#pragma unroll 2
    for (int kc = 0; kc < 4; ++kc) {
        short8v bh[4];
#pragma unroll
        for (int nt = 0; nt < 4; ++nt)
            bh[nt] = *reinterpret_cast<const short8v*>(&Bs[kc][nt][lane][0]);
#pragma unroll
        for (int mi = 0; mi < 2; ++mi) {
            const int m = wv*2 + mi;
            const size_t off = (size_t)((m*4 + kc)*64 + lane)*8;
            const short8v arh = *reinterpret_cast<const short8v*>(Are_hi + off);
            const short8v arl = *reinterpret_cast<const short8v*>(Are_lo + off);
            const short8v aih = *reinterpret_cast<const short8v*>(Aim_hi + off);
            const short8v ail = *reinterpret_cast<const short8v*>(Aim_lo + off);
#pragma unroll
            for (int nt = 0; nt < 4; ++nt) {
                accRe[mi][nt] = __builtin_amdgcn_mfma_f32_16x16x32_bf16(arh, bh[nt], accRe[mi][nt], 0, 0, 0);
                accRe[mi][nt] = __builtin_amdgcn_mfma_f32_16x16x32_bf16(arl, bh[nt], accRe[mi][nt], 0, 0, 0);
                accIm[mi][nt] = __builtin_amdgcn_mfma_f32_16x16x32_bf16(aih, bh[nt], accIm[mi][nt], 0, 0, 0);
                accIm[mi][nt] = __builtin_amdgcn_mfma_f32_16x16x32_bf16(ail, bh[nt], accIm[mi][nt], 0, 0, 0);
            }
        }
    }

    const int col   = lane & 15;
    const int rbase = (lane >> 4) * 4;
#pragma unroll
    for (int mi = 0; mi < 2; ++mi) {
#pragma unroll
        for (int r = 0; r < 4; ++r) {
            const int o = wv*32 + mi*16 + rbase + r;
#pragma unroll
            for (int nt = 0; nt < 4; ++nt) {
                const int wcol = nt*16 + col;
                float2 rv = make_float2(accRe[mi][nt][r], accIm[mi][nt][r]);
                Sout[(size_t)bl*CHW + (size_t)o*HW + tt*64 + wcol] = pack2bf(rv);
            }
        }
    }
}

// ---- forward FFT along H + bias(w==0) + gamma (verified r16) ----------
__global__ __launch_bounds__(256) void fft_gamma_kernel(
    const unsigned* __restrict__ Hsp,
    unsigned* __restrict__ Hfq,
    const float* __restrict__ gamma_tab,
    const float* __restrict__ bb_re, const float* __restrict__ bb_im)
{
    const int gid = blockIdx.x*256 + threadIdx.x;     // 0..262143
    const int w = gid & 31;
    const size_t slice = (size_t)(gid >> 5);          // (b,l,c)
    const int c = (int)(slice & 127);
    const unsigned* src = Hsp + slice*HW + w;
    float2 v[32];
#pragma unroll
    for (int i = 0; i < 32; ++i)
        v[i] = unpack2bf(src[(size_t)bitrev5(i)*Wdim]);
    fft32_reg<0>(v);
    const float br = (w == 0) ? bb_re[c] : 0.0f;
    const float bi = (w == 0) ? bb_im[c] : 0.0f;
    const float* gt = gamma_tab + c*32;
    unsigned* dst = Hfq + slice*HW + w;
#pragma unroll
    for (int hf = 0; hf < 32; ++hf) {
        const float g = gt[hf];
        dst[(size_t)hf*Wdim] = pack2bf(make_float2((v[hf].x + br)*g, (v[hf].y + bi)*g));
    }
}

// ---- inverse FFT along H (verified r13) ----
__global__ __launch_bounds__(256) void ifft_h_bf_kernel(const unsigned* __restrict__ Sin,
                                                        unsigned* __restrict__ Ysp) {
    const int gid = blockIdx.x*256 + threadIdx.x;
    const int w = gid & 31;
    const size_t slice = (size_t)(gid >> 5);
    const unsigned* src = Sin + slice*HW + w;
    float2 v[32];
#pragma unroll
    for (int i = 0; i < 32; ++i)
        v[i] = unpack2bf(src[(size_t)bitrev5(i)*Wdim]);
    fft32_reg<1>(v);
    const float sc = 1.0f / 32.0f;
    unsigned* dst = Ysp + slice*HW + w;
#pragma unroll
    for (int h = 0; h < 32; ++h)
        dst[(size_t)h*Wdim] = pack2bf(make_float2(v[h].x*sc, v[h].y*sc));
}

// ======================= scan over L + fused FFT_W for out1 (verified r14) =
template<int CPLX>
__global__ __launch_bounds__(256) void scan_fftw_kernel(
    unsigned* __restrict__ Hf2, const float* __restrict__ pl, float* __restrict__ out1)
{
    const int idx = blockIdx.x*256 + threadIdx.x;   // 0..262143 = B*C*H*W
    const int b   = idx >> 17;
    const int chw = idx & (CHW - 1);
    const int c   = chw >> 10;
    const int h   = (chw >> 5) & 31;
    const float nu = expf(pl[c*Hdim + h]);
    const float th = expf(pl[(Cdim + c)*Hdim + h]);
    const float rr = expf(-nu);
    const float lr = rr * cosf(th);
    const float li = rr * sinf(th);
    float2 y = make_float2(0.f, 0.f);
    const size_t basei = (size_t)b * Ldim * CHW + chw;
#pragma unroll 4
    for (int l = 0; l < Ldim; ++l) {
        float2 hv = unpack2bf(Hf2[basei + (size_t)l*CHW]);
        float yr = fmaf(lr, y.x, fmaf(-li, y.y, hv.x));
        float yi = fmaf(lr, y.y, fmaf( li, y.x, hv.y));
        y = make_float2(yr, yi);
        Hf2[basei + (size_t)l*CHW] = pack2bf(y);
    }
    const int a = threadIdx.x & 31;            // DIT slot
    float2 v;
    v.x = __shfl(y.x, bitrev5(a), 32);
    v.y = __shfl(y.y, bitrev5(a), 32);
#pragma unroll
    for (int st = 0; st < 5; ++st) {
        const int half = 1 << st;
        const int j = a & (half - 1);
        const float ang = -6.283185307179586f * (float)(j << (4 - st)) / 32.0f;
        float wi, wr;
        __sincosf(ang, &wi, &wr);
        float2 p;
        p.x = __shfl_xor(v.x, half, 32);
        p.y = __shfl_xor(v.y, half, 32);
        const bool top = (a & half) == 0;
        const float2 a1 = top ? p : v;
        const float2 a0 = top ? v : p;
        const float tr = wr*a1.x - wi*a1.y;
        const float ti = wr*a1.y + wi*a1.x;
        v.x = top ? a0.x + tr : a0.x - tr;
        v.y = top ? a0.y + ti : a0.y - ti;
    }
    const size_t row = (size_t)(idx >> 5);     // (b,c,hf)
    if (CPLX) {
        reinterpret_cast<float2*>(out1)[row*32 + a] = v;
    } else {
        out1[row*32 + a] = v.x;
    }
}

// ======================= COOPERATIVE: Wc-mix + full LayerNorm + residual ==========
// Phase 1: verified mix1 body, acc += bc (kept in registers), per-block LN partials.
// grid.sync().  Phase 2: reduce this bl's 16 partials.  Phase 3: LN+residual from
// registers -> f32 out0.  1024 blocks @ 4/CU co-resident (LDS 32KB, VGPR<=128).
__global__ __launch_bounds__(256, 4) void mix1_ln_coop_kernel(
    const unsigned* __restrict__ Yin,
    const short* __restrict__ Apack,
    const float* __restrict__ bre,
    const float* __restrict__ x,
    const float* __restrict__ lnw, const float* __restrict__ lnb,
    float* __restrict__ out0,
    float2* __restrict__ lnpart)
{
    __shared__ short Bs[8][4][64][8];    // 32 KB
    const int bx = blockIdx.x;           // 64 bl * 16 tt
    const int bl = bx >> 4, tt = bx & 15;
    const int t = threadIdx.x;
    const int wv = t >> 6, lane = t & 63;

    const unsigned* src = Yin + (size_t)bl*CHW + tt*64;
#pragma unroll
    for (int g = 0; g < 4; ++g) {
        const int id = g*256 + t;
        const int hw = id & 63;
        const int co = id >> 6;
        const int kc = co >> 2;
        const int ln = (co & 3)*16 + (hw & 15);
        const int nt4 = hw >> 4;
        unsigned u[8];
#pragma unroll
        for (int j = 0; j < 8; ++j)
            u[j] = src[(size_t)(co*8 + j)*HW + hw];
        unsigned re[4], im[4];
#pragma unroll
        for (int p = 0; p < 4; ++p) {
            re[p] = (u[2*p] & 0xFFFFu) | (u[2*p+1] << 16);
            im[p] = (u[2*p] >> 16) | (u[2*p+1] & 0xFFFF0000u);
        }
        *reinterpret_cast<uint4*>(&Bs[kc][nt4][ln][0])   = make_uint4(re[0], re[1], re[2], re[3]);
        *reinterpret_cast<uint4*>(&Bs[kc+4][nt4][ln][0]) = make_uint4(im[0], im[1], im[2], im[3]);
    }
    __syncthreads();

    f32x4 acc[2][4];
#pragma unroll
    for (int mi = 0; mi < 2; ++mi)
#pragma unroll
        for (int nt = 0; nt < 4; ++nt) acc[mi][nt] = (f32x4)(0.0f);

    const short* A_hi = Apack + 65536;
    const short* A_lo = Apack + 65536 + 32768;

#pragma unroll 2
    for (int kc = 0; kc < 8; ++kc) {
        short8v bh[4];
#pragma unroll
        for (int nt = 0; nt < 4; ++nt)
            bh[nt] = *reinterpret_cast<const short8v*>(&Bs[kc][nt][lane][0]);
#pragma unroll
        for (int mi = 0; mi < 2; ++mi) {
            const int m = wv*2 + mi;
            const size_t off = (size_t)((m*8 + kc)*64 + lane)*8;
            const short8v arh = *reinterpret_cast<const short8v*>(A_hi + off);
            const short8v arl = *reinterpret_cast<const short8v*>(A_lo + off);
#pragma unroll
            for (int nt = 0; nt < 4; ++nt) {
                acc[mi][nt] = __builtin_amdgcn_mfma_f32_16x16x32_bf16(arh, bh[nt], acc[mi][nt], 0, 0, 0);
                acc[mi][nt] = __builtin_amdgcn_mfma_f32_16x16x32_bf16(arl, bh[nt], acc[mi][nt], 0, 0, 0);
            }
        }
    }

    const int col   = lane & 15;
    const int rbase = (lane >> 4) * 4;
    float lns = 0.f, lnq = 0.f;
#pragma unroll
    for (int mi = 0; mi < 2; ++mi) {
#pragma unroll
        for (int r = 0; r < 4; ++r) {
            const int o = wv*32 + mi*16 + rbase + r;
            const float br = bre[o];
#pragma unroll
            for (int nt = 0; nt < 4; ++nt) {
                const float v = acc[mi][nt][r] + br;
                acc[mi][nt][r] = v;              // keep biased value in registers
                lns += v; lnq += v*v;
            }
        }
    }
#pragma unroll
    for (int off = 32; off > 0; off >>= 1) {
        lns += __shfl_down(lns, off);
        lnq += __shfl_down(lnq, off);
    }
    __shared__ float2 red[4];
    if (lane == 0) red[wv] = make_float2(lns, lnq);
    __syncthreads();
    if (t == 0) {
        float2 a = red[0], b2 = red[1], c2 = red[2], d = red[3];
        lnpart[bx] = make_float2(a.x + b2.x + c2.x + d.x, a.y + b2.y + c2.y + d.y);
    }
    __threadfence();

    cg::this_grid().sync();

    // ---- phase 2: reduce this bl's 16 partials (wave 0), broadcast via LDS ----
    __shared__ float2 mstat;
    if (t < 64) {
        float s = 0.f, sq = 0.f;
        if (t < 16) { float2 v = lnpart[bl*16 + t]; s = v.x; sq = v.y; }
#pragma unroll
        for (int off = 8; off > 0; off >>= 1) {
            s  += __shfl_down(s, off);
            sq += __shfl_down(sq, off);
        }
        if (t == 0) {
            const float invN = 1.0f / (float)CHW;
            const float mean = s * invN;
            const float var  = sq * invN - mean*mean;
            mstat = make_float2(mean, rsqrtf(var + 1e-5f));
        }
    }
    __syncthreads();
    const float m  = mstat.x;
    const float rs = mstat.y;

    // ---- phase 3: LN + residual from registers ----
#pragma unroll
    for (int mi = 0; mi < 2; ++mi) {
#pragma unroll
        for (int r = 0; r < 4; ++r) {
            const int o = wv*32 + mi*16 + rbase + r;
#pragma unroll
            for (int nt = 0; nt < 4; ++nt) {
                const int wcol = nt*16 + col;
                const size_t cidx = (size_t)o*HW + tt*64 + wcol;
                const size_t gidx = (size_t)bl*CHW + cidx;
                const float v = acc[mi][nt][r];
                out0[gidx] = fmaf((v - m)*rs, lnw[cidx], lnb[cidx]) + x[gidx];
            }
        }
    }
}

// ======================= fallback: mix1 (verified r16) + ln_apply w/ folded finish =
__global__ __launch_bounds__(256) void mix1_kernel(
    const unsigned* __restrict__ Yin,
    const short* __restrict__ Apack,
    const float* __restrict__ bre,
    unsigned short* __restrict__ outr,
    float2* __restrict__ lnpart)
{
    __shared__ short Bs[8][4][64][8];    // 32 KB
    const int bx = blockIdx.x;
    const int bl = bx >> 4, tt = bx & 15;
    const int t = threadIdx.x;
    const int wv = t >> 6, lane = t & 63;

    const unsigned* src = Yin + (size_t)bl*CHW + tt*64;
#pragma unroll
    for (int g = 0; g < 4; ++g) {
        const int id = g*256 + t;
        const int hw = id & 63;
        const int co = id >> 6;
        const int kc = co >> 2;
        const int ln = (co & 3)*16 + (hw & 15);
        const int nt4 = hw >> 4;
        unsigned u[8];
#pragma unroll
        for (int j = 0; j < 8; ++j)
            u[j] = src[(size_t)(co*8 + j)*HW + hw];
        unsigned re[4], im[4];
#pragma unroll
        for (int p = 0; p < 4; ++p) {
            re[p] = (u[2*p] & 0xFFFFu) | (u[2*p+1] << 16);
            im[p] = (u[2*p] >> 16) | (u[2*p+1] & 0xFFFF0000u);
        }
        *reinterpret_cast<uint4*>(&Bs[kc][nt4][ln][0])   = make_uint4(re[0], re[1], re[2], re[3]);
        *reinterpret_cast<uint4*>(&Bs[kc+4][nt4][ln][0]) = make_uint4(im[0], im[1], im[2], im[3]);
    }
    __syncthreads();

    f32x4 acc[2][4];
#pragma unroll
    for (int mi = 0; mi < 2; ++mi)
#pragma unroll
        for (int nt = 0; nt < 4; ++nt) acc[mi][nt] = (f32x4)(0.0f);

    const short* A_hi = Apack + 65536;
    const short* A_lo = Apack + 65536 + 32768;

#pragma unroll 2
    for (int kc = 0; kc < 8; ++kc) {
        short8v bh[4];
#pragma unroll
        for (int nt = 0; nt < 4; ++nt)
            bh[nt] = *reinterpret_cast<const short8v*>(&Bs[kc][nt][lane][0]);
#pragma unroll
        for (int mi = 0; mi < 2; ++mi) {
            const int m = wv*2 + mi;
            const size_t off = (size_t)((m*8 + kc)*64 + lane)*8;
            const short8v arh = *reinterpret_cast<const short8v*>(A_hi + off);
            const short8v arl = *reinterpret_cast<const short8v*>(A_lo + off);
#pragma unroll
            for (int nt = 0; nt < 4; ++nt) {
                acc[mi][nt] = __builtin_amdgcn_mfma_f32_16x16x32_bf16(arh, bh[nt], acc[mi][nt], 0, 0, 0);
                acc[mi][nt] = __builtin_amdgcn_mfma_f32_16x16x32_bf16(arl, bh[nt], acc[mi][nt], 0, 0, 0);
            }
        }
    }

    const int col   = lane & 15;
    const int rbase = (lane >> 4) * 4;
    float lns = 0.f, lnq = 0.f;
#pragma unroll
    for (int mi = 0; mi < 2; ++mi) {
#pragma unroll
        for (int r = 0; r < 4; ++r) {
            const int o = wv*32 + mi*16 + rbase + r;
            const float br = bre[o];
#pragma unroll
            for (int nt = 0; nt < 4; ++nt) {
                const int wcol = nt*16 + col;
                const float v = acc[mi][nt][r] + br;
                outr[(size_t)bl*CHW + (size_t)o*HW + tt*64 + wcol] = f2bf(v);
                lns += v; lnq += v*v;
            }
        }
    }
#pragma unroll
    for (int off = 32; off > 0; off >>= 1) {
        lns += __shfl_down(lns, off);
        lnq += __shfl_down(lnq, off);
    }
    __shared__ float2 red[4];
    if (lane == 0) red[wv] = make_float2(lns, lnq);
    __syncthreads();
    if (t == 0) {
        float2 a = red[0], b2 = red[1], c2 = red[2], d = red[3];
        lnpart[bx] = make_float2(a.x + b2.x + c2.x + d.x, a.y + b2.y + c2.y + d.y);
    }
}

__global__ __launch_bounds__(256) void ln_apply2_kernel(
    float* __restrict__ out0, const unsigned short* __restrict__ hpre,
    const float* __restrict__ x,
    const float* __restrict__ lnw, const float* __restrict__ lnb,
    const float2* __restrict__ lnpart)
{
    const int idx4 = blockIdx.x*256 + threadIdx.x;   // 4 elems per thread
    const int i = idx4 * 4;
    const int bl = i >> 17;                          // whole block shares one bl
    // fold ln_finish: reduce this bl's 16 partials in wave 0, broadcast via LDS
    __shared__ float2 mstat;
    const int t = threadIdx.x;
    if (t < 64) {
        float s = 0.f, sq = 0.f;
        if (t < 16) { float2 v = lnpart[bl*16 + t]; s = v.x; sq = v.y; }
#pragma unroll
        for (int off = 8; off > 0; off >>= 1) {
            s  += __shfl_down(s, off);
            sq += __shfl_down(sq, off);
        }
        if (t == 0) {
            const float invN = 1.0f / (float)CHW;
            const float mean = s * invN;
            const float var  = sq * invN - mean*mean;
            mstat = make_float2(mean, rsqrtf(var + 1e-5f));
        }
    }
    __syncthreads();
    const float m = mstat.x, rs = mstat.y;

    const int chw4 = (i & (CHW - 1)) >> 2;
    const uint2 hu = reinterpret_cast<const uint2*>(hpre)[idx4];
    float4 h;
    h.x = __uint_as_float(hu.x << 16);
    h.y = __uint_as_float(hu.x & 0xFFFF0000u);
    h.z = __uint_as_float(hu.y << 16);
    h.w = __uint_as_float(hu.y & 0xFFFF0000u);
    float4 xv = reinterpret_cast<const float4*>(x)[idx4];
    float4 w  = reinterpret_cast<const float4*>(lnw)[chw4];
    float4 bb = reinterpret_cast<const float4*>(lnb)[chw4];
    float4 r;
    r.x = fmaf((h.x - m)*rs, w.x, bb.x) + xv.x;
    r.y = fmaf((h.y - m)*rs, w.y, bb.y) + xv.y;
    r.z = fmaf((h.z - m)*rs, w.z, bb.z) + xv.z;
    r.w = fmaf((h.w - m)*rs, w.w, bb.w) + xv.w;
    reinterpret_cast<float4*>(out0)[idx4] = r;
}

// ======================= launch =======================
extern "C" void kernel_launch(void* const* d_in, const int* in_sizes, int n_in,
                              void* d_out, int out_size, void* d_ws, size_t ws_size,
                              hipStream_t stream)
{
    const float* x     = (const float*)d_in[0];
    const float* pl    = (const float*)d_in[1];
    const float* Wb_re = (const float*)d_in[2];
    const float* Wb_im = (const float*)d_in[3];
    const float* bb_re = (const float*)d_in[4];
    const float* bb_im = (const float*)d_in[5];
    const float* Wc_re = (const float*)d_in[6];
    const float* Wc_im = (const float*)d_in[7];
    const float* bc_re = (const float*)d_in[8];
    const float* bc_im = (const float*)d_in[9];
    const float* ln_w  = (const float*)d_in[10];
    const float* ln_b  = (const float*)d_in[11];
    (void)bc_im;

    float* out0 = (float*)d_out;
    float* out1 = out0 + OUT0_ELEMS;

    char* ws = (char*)d_ws;
    unsigned*       bufA    = (unsigned*)       ws;                        // 33,554,432
    unsigned*       bufB    = (unsigned*)       (ws + 33554432);           // 33,554,432
    unsigned short* out0pre = (unsigned short*) (ws + 67108864);           // 16,777,216 (fallback only)
    short*          Apack   = (short*)          (ws + 83886080);           //    262,144
    float*          gtab    = (float*)          (ws + 84148224);           //     16,384
    float2*         lnpart  = (float2*)         (ws + 84164608);           //      8,192

    const bool interleaved = ((size_t)out_size >= OUT0_ELEMS + 2*OUT1_CPLX);

    pack_w_kernel<<<48, 256, 0, stream>>>(Wb_re, Wb_im, Wc_re, Wc_im, pl, Apack, gtab);
    mix0_spatial_kernel<<<1024, 256, 0, stream>>>(x, bufA, Apack);
    fft_gamma_kernel<<<1024, 256, 0, stream>>>(bufA, bufB, gtab, bb_re, bb_im);
    if (interleaved)
        scan_fftw_kernel<1><<<1024, 256, 0, stream>>>(bufB, pl, out1);
    else
        scan_fftw_kernel<0><<<1024, 256, 0, stream>>>(bufB, pl, out1);
    ifft_h_bf_kernel<<<1024, 256, 0, stream>>>(bufB, bufA);

    // cooperative mix1+LN; fall back to verified 2-kernel path on launch failure
    {
        const unsigned* yinArg = bufA;
        const short*    apArg  = Apack;
        const float*    brArg  = bc_re;
        const float*    xArg   = x;
        const float*    lwArg  = ln_w;
        const float*    lbArg  = ln_b;
        float*          o0Arg  = out0;
        float2*         lpArg  = lnpart;
        void* args[] = { (void*)&yinArg, (void*)&apArg, (void*)&brArg, (void*)&xArg,
                         (void*)&lwArg, (void*)&lbArg, (void*)&o0Arg, (void*)&lpArg };
        hipError_t err = hipLaunchCooperativeKernel(
            (const void*)mix1_ln_coop_kernel, dim3(1024), dim3(256), args, 0, stream);
        if (err != hipSuccess) {
            mix1_kernel<<<1024, 256, 0, stream>>>(bufA, Apack, bc_re, out0pre, lnpart);
            ln_apply2_kernel<<<8192, 256, 0, stream>>>(out0, out0pre, x, ln_w, ln_b, lnpart);
        }
    }
}

// Round 18
// 96.609 us; speedup vs baseline: 2.0980x; 2.0980x over previous
//
#include <hip/hip_runtime.h>
#include <cstdint>
#include <cstddef>

#define DEVINL __device__ __forceinline__

static constexpr int Bdim = 2, Ldim = 32, Cdim = 128, Hdim = 32, Wdim = 32;
static constexpr int HW  = Hdim * Wdim;         // 1024
static constexpr int CHW = Cdim * HW;           // 131072
static constexpr size_t OUT0_ELEMS = (size_t)Bdim * Ldim * CHW;  // 8388608
static constexpr size_t OUT1_CPLX  = (size_t)Bdim * CHW;         // 262144 complex elems

typedef __attribute__((ext_vector_type(8))) short short8v;   // 8 bf16 (4 VGPR)
typedef __attribute__((ext_vector_type(4))) float f32x4;     // MFMA C/D

DEVINL int bitrev5(int v) {
    return ((v&1)<<4) | ((v&2)<<2) | (v&4) | ((v&8)>>2) | ((v&16)>>4);
}
DEVINL unsigned short f2bf(float v) {               // RNE f32 -> bf16 bits
    unsigned u = __float_as_uint(v);
    return (unsigned short)((u + 0x7FFFu + ((u >> 16) & 1u)) >> 16);
}
DEVINL void bfsplit(float v, short& hi, short& lo) {
    unsigned short hb = f2bf(v);
    hi = (short)hb;
    float hf = __uint_as_float(((unsigned)hb) << 16);
    lo = (short)f2bf(v - hf);
}
DEVINL unsigned pack2bf(float2 v) {
    return (unsigned)f2bf(v.x) | ((unsigned)f2bf(v.y) << 16);
}
DEVINL float2 unpack2bf(unsigned u) {
    return make_float2(__uint_as_float(u << 16), __uint_as_float(u & 0xFFFF0000u));
}

// ================= 32-point radix-2 DIT FFT, fully in registers =================
template<int INV>
DEVINL void fft32_reg(float2 v[32]) {
    constexpr float TC[16] = { 1.0f, 0.980785280f, 0.923879533f, 0.831469612f,
                               0.707106781f, 0.555570233f, 0.382683432f, 0.195090322f,
                               0.0f, -0.195090322f, -0.382683432f, -0.555570233f,
                              -0.707106781f, -0.831469612f, -0.923879533f, -0.980785280f };
    constexpr float TS[16] = { 0.0f, -0.195090322f, -0.382683432f, -0.555570233f,
                              -0.707106781f, -0.831469612f, -0.923879533f, -0.980785280f,
                              -1.0f, -0.980785280f, -0.923879533f, -0.831469612f,
                              -0.707106781f, -0.555570233f, -0.382683432f, -0.195090322f };
#pragma unroll
    for (int st = 0; st < 5; ++st) {
        const int half = 1 << st;
#pragma unroll
        for (int bf = 0; bf < 16; ++bf) {
            const int g = bf >> st;
            const int j = bf & (half - 1);
            const int i0 = (g << (st+1)) + j;
            const float wr = TC[j << (4-st)];
            const float wi = INV ? -TS[j << (4-st)] : TS[j << (4-st)];
            float2 a0 = v[i0], a1 = v[i0+half];
            float tr = wr*a1.x - wi*a1.y;
            float ti = wr*a1.y + wi*a1.x;
            v[i0]      = make_float2(a0.x+tr, a0.y+ti);
            v[i0+half] = make_float2(a0.x-tr, a0.y-ti);
        }
    }
}

// ======================= A-pack + gamma table (verified r16) ==========
__global__ __launch_bounds__(256) void pack_w_kernel(
    const float* __restrict__ Wb_re, const float* __restrict__ Wb_im,
    const float* __restrict__ Wc_re, const float* __restrict__ Wc_im,
    const float* __restrict__ pl,
    short* __restrict__ Apack, float* __restrict__ gamma_tab)
{
    const int gid = blockIdx.x*256 + threadIdx.x;    // 0..12287
    if (gid < 4096) {                                 // Wb re/im, K=128
        const int a2   = gid >> 11;
        const int rem  = gid & 2047;
        const int f    = rem >> 6;
        const int lane = rem & 63;
        const int m  = f >> 2, kc = f & 3;
        const int row = m*16 + (lane & 15);
        const int kbase = kc*32 + ((lane >> 4) << 3);
        short8v hi8, lo8;
#pragma unroll
        for (int j = 0; j < 8; ++j) {
            const int c = kbase + j;
            const float v = a2 ? Wb_im[row*Cdim + c] : Wb_re[row*Cdim + c];
            short h, l; bfsplit(v, h, l);
            hi8[j] = h; lo8[j] = l;
        }
        const size_t off = (size_t)(f*64 + lane)*8;
        const size_t base = (size_t)a2 * 32768;
        *reinterpret_cast<short8v*>(Apack + base + off)         = hi8;
        *reinterpret_cast<short8v*>(Apack + base + 16384 + off) = lo8;
    } else if (gid < 8192) {                          // Wc, K=256
        const int rem  = gid - 4096;
        const int f    = rem >> 6;
        const int lane = rem & 63;
        const int m  = f >> 3, kc = f & 7;
        const int row = m*16 + (lane & 15);
        const int kbase = kc*32 + ((lane >> 4) << 3);
        short8v hi8, lo8;
#pragma unroll
        for (int j = 0; j < 8; ++j) {
            const int k = kbase + j;
            const int half = k >> 7;
            const int c = k & 127;
            const float v = half ? -Wc_im[row*Cdim + c] : Wc_re[row*Cdim + c];
            short h, l; bfsplit(v, h, l);
            hi8[j] = h; lo8[j] = l;
        }
        const size_t off = (size_t)(f*64 + lane)*8;
        *reinterpret_cast<short8v*>(Apack + 65536 + off)         = hi8;
        *reinterpret_cast<short8v*>(Apack + 65536 + 32768 + off) = lo8;
    } else {                                          // gamma table
        const int idx = gid - 8192;
        const int c = idx >> 5, hf = idx & 31;
        gamma_tab[idx] = expf(pl[(2*Cdim + c)*Hdim + hf]);
    }
}

// ======================= spatial Wb-mix (verified r16) ================
__global__ __launch_bounds__(256) void mix0_spatial_kernel(
    const float* __restrict__ x,
    unsigned* __restrict__ Sout,
    const short* __restrict__ Apack)
{
    __shared__ short Bs[4][4][64][8];    // 16 KB
    const int bx = blockIdx.x;           // 64 bl * 16 tt
    const int bl = bx >> 4, tt = bx & 15;
    const int t = threadIdx.x;
    const int wv = t >> 6, lane = t & 63;

    const float* src = x + (size_t)bl*CHW + tt*64;
#pragma unroll
    for (int g = 0; g < 4; ++g) {
        const int id = g*256 + t;
        const int hw = id & 63;
        const int co = id >> 6;
        const int kc = co >> 2;
        const int ln = (co & 3)*16 + (hw & 15);
        const int nt4 = hw >> 4;
        short8v b8;
#pragma unroll
        for (int j = 0; j < 8; ++j)
            b8[j] = (short)f2bf(src[(size_t)(co*8 + j)*HW + hw]);
        *reinterpret_cast<short8v*>(&Bs[kc][nt4][ln][0]) = b8;
    }
    __syncthreads();

    f32x4 accRe[2][4];
    f32x4 accIm[2][4];
#pragma unroll
    for (int mi = 0; mi < 2; ++mi)
#pragma unroll
        for (int nt = 0; nt < 4; ++nt) {
            accRe[mi][nt] = (f32x4)(0.0f);
            accIm[mi][nt] = (f32x4)(0.0f);
        }

    const short* Are_hi = Apack;
    const short* Are_lo = Apack + 16384;
    const short* Aim_hi = Apack + 32768;
    const short* Aim_lo = Apack + 49152;

#pragma unroll 2
    for (int kc = 0; kc < 4; ++kc) {
        short8v bh[4];
#pragma unroll
        for (int nt = 0; nt < 4; ++nt)
            bh[nt] = *reinterpret_cast<const short8v*>(&Bs[kc][nt][lane][0]);
#pragma unroll
        for (int mi = 0; mi < 2; ++mi) {
            const int m = wv*2 + mi;
            const size_t off = (size_t)((m*4 + kc)*64 + lane)*8;
            const short8v arh = *reinterpret_cast<const short8v*>(Are_hi + off);
            const short8v arl = *reinterpret_cast<const short8v*>(Are_lo + off);
            const short8v aih = *reinterpret_cast<const short8v*>(Aim_hi + off);
            const short8v ail = *reinterpret_cast<const short8v*>(Aim_lo + off);
#pragma unroll
            for (int nt = 0; nt < 4; ++nt) {
                accRe[mi][nt] = __builtin_amdgcn_mfma_f32_16x16x32_bf16(arh, bh[nt], accRe[mi][nt], 0, 0, 0);
                accRe[mi][nt] = __builtin_amdgcn_mfma_f32_16x16x32_bf16(arl, bh[nt], accRe[mi][nt], 0, 0, 0);
                accIm[mi][nt] = __builtin_amdgcn_mfma_f32_16x16x32_bf16(aih, bh[nt], accIm[mi][nt], 0, 0, 0);
                accIm[mi][nt] = __builtin_amdgcn_mfma_f32_16x16x32_bf16(ail, bh[nt], accIm[mi][nt], 0, 0, 0);
            }
        }
    }

    const int col   = lane & 15;
    const int rbase = (lane >> 4) * 4;
#pragma unroll
    for (int mi = 0; mi < 2; ++mi) {
#pragma unroll
        for (int r = 0; r < 4; ++r) {
            const int o = wv*32 + mi*16 + rbase + r;
#pragma unroll
            for (int nt = 0; nt < 4; ++nt) {
                const int wcol = nt*16 + col;
                float2 rv = make_float2(accRe[mi][nt][r], accIm[mi][nt][r]);
                Sout[(size_t)bl*CHW + (size_t)o*HW + tt*64 + wcol] = pack2bf(rv);
            }
        }
    }
}

// ---- forward FFT along H + bias(w==0) + gamma (verified r16) ----------
__global__ __launch_bounds__(256) void fft_gamma_kernel(
    const unsigned* __restrict__ Hsp,
    unsigned* __restrict__ Hfq,
    const float* __restrict__ gamma_tab,
    const float* __restrict__ bb_re, const float* __restrict__ bb_im)
{
    const int gid = blockIdx.x*256 + threadIdx.x;     // 0..262143
    const int w = gid & 31;
    const size_t slice = (size_t)(gid >> 5);          // (b,l,c)
    const int c = (int)(slice & 127);
    const unsigned* src = Hsp + slice*HW + w;
    float2 v[32];
#pragma unroll
    for (int i = 0; i < 32; ++i)
        v[i] = unpack2bf(src[(size_t)bitrev5(i)*Wdim]);
    fft32_reg<0>(v);
    const float br = (w == 0) ? bb_re[c] : 0.0f;
    const float bi = (w == 0) ? bb_im[c] : 0.0f;
    const float* gt = gamma_tab + c*32;
    unsigned* dst = Hfq + slice*HW + w;
#pragma unroll
    for (int hf = 0; hf < 32; ++hf) {
        const float g = gt[hf];
        dst[(size_t)hf*Wdim] = pack2bf(make_float2((v[hf].x + br)*g, (v[hf].y + bi)*g));
    }
}

// ---- inverse FFT along H (verified r13) ----
__global__ __launch_bounds__(256) void ifft_h_bf_kernel(const unsigned* __restrict__ Sin,
                                                        unsigned* __restrict__ Ysp) {
    const int gid = blockIdx.x*256 + threadIdx.x;
    const int w = gid & 31;
    const size_t slice = (size_t)(gid >> 5);
    const unsigned* src = Sin + slice*HW + w;
    float2 v[32];
#pragma unroll
    for (int i = 0; i < 32; ++i)
        v[i] = unpack2bf(src[(size_t)bitrev5(i)*Wdim]);
    fft32_reg<1>(v);
    const float sc = 1.0f / 32.0f;
    unsigned* dst = Ysp + slice*HW + w;
#pragma unroll
    for (int h = 0; h < 32; ++h)
        dst[(size_t)h*Wdim] = pack2bf(make_float2(v[h].x*sc, v[h].y*sc));
}

// ======================= scan over L + fused FFT_W for out1 (verified r14) =
template<int CPLX>
__global__ __launch_bounds__(256) void scan_fftw_kernel(
    unsigned* __restrict__ Hf2, const float* __restrict__ pl, float* __restrict__ out1)
{
    const int idx = blockIdx.x*256 + threadIdx.x;   // 0..262143 = B*C*H*W
    const int b   = idx >> 17;
    const int chw = idx & (CHW - 1);
    const int c   = chw >> 10;
    const int h   = (chw >> 5) & 31;
    const float nu = expf(pl[c*Hdim + h]);
    const float th = expf(pl[(Cdim + c)*Hdim + h]);
    const float rr = expf(-nu);
    const float lr = rr * cosf(th);
    const float li = rr * sinf(th);
    float2 y = make_float2(0.f, 0.f);
    const size_t basei = (size_t)b * Ldim * CHW + chw;
#pragma unroll 4
    for (int l = 0; l < Ldim; ++l) {
        float2 hv = unpack2bf(Hf2[basei + (size_t)l*CHW]);
        float yr = fmaf(lr, y.x, fmaf(-li, y.y, hv.x));
        float yi = fmaf(lr, y.y, fmaf( li, y.x, hv.y));
        y = make_float2(yr, yi);
        Hf2[basei + (size_t)l*CHW] = pack2bf(y);
    }
    const int a = threadIdx.x & 31;            // DIT slot
    float2 v;
    v.x = __shfl(y.x, bitrev5(a), 32);
    v.y = __shfl(y.y, bitrev5(a), 32);
#pragma unroll
    for (int st = 0; st < 5; ++st) {
        const int half = 1 << st;
        const int j = a & (half - 1);
        const float ang = -6.283185307179586f * (float)(j << (4 - st)) / 32.0f;
        float wi, wr;
        __sincosf(ang, &wi, &wr);
        float2 p;
        p.x = __shfl_xor(v.x, half, 32);
        p.y = __shfl_xor(v.y, half, 32);
        const bool top = (a & half) == 0;
        const float2 a1 = top ? p : v;
        const float2 a0 = top ? v : p;
        const float tr = wr*a1.x - wi*a1.y;
        const float ti = wr*a1.y + wi*a1.x;
        v.x = top ? a0.x + tr : a0.x - tr;
        v.y = top ? a0.y + ti : a0.y - ti;
    }
    const size_t row = (size_t)(idx >> 5);     // (b,c,hf)
    if (CPLX) {
        reinterpret_cast<float2*>(out1)[row*32 + a] = v;
    } else {
        out1[row*32 + a] = v.x;
    }
}

// ======================= MFMA Wc-mix (real out) + LN partials (verified r16) ==
__global__ __launch_bounds__(256) void mix1_kernel(
    const unsigned* __restrict__ Yin,
    const short* __restrict__ Apack,
    const float* __restrict__ bre,
    unsigned short* __restrict__ outr,
    float2* __restrict__ lnpart)
{
    __shared__ short Bs[8][4][64][8];    // 32 KB
    const int bx = blockIdx.x;           // 64 bl * 16 tt
    const int bl = bx >> 4, tt = bx & 15;
    const int t = threadIdx.x;
    const int wv = t >> 6, lane = t & 63;

    const unsigned* src = Yin + (size_t)bl*CHW + tt*64;
#pragma unroll
    for (int g = 0; g < 4; ++g) {
        const int id = g*256 + t;
        const int hw = id & 63;
        const int co = id >> 6;
        const int kc = co >> 2;
        const int ln = (co & 3)*16 + (hw & 15);
        const int nt4 = hw >> 4;
        unsigned u[8];
#pragma unroll
        for (int j = 0; j < 8; ++j)
            u[j] = src[(size_t)(co*8 + j)*HW + hw];
        unsigned re[4], im[4];
#pragma unroll
        for (int p = 0; p < 4; ++p) {
            re[p] = (u[2*p] & 0xFFFFu) | (u[2*p+1] << 16);
            im[p] = (u[2*p] >> 16) | (u[2*p+1] & 0xFFFF0000u);
        }
        *reinterpret_cast<uint4*>(&Bs[kc][nt4][ln][0])   = make_uint4(re[0], re[1], re[2], re[3]);
        *reinterpret_cast<uint4*>(&Bs[kc+4][nt4][ln][0]) = make_uint4(im[0], im[1], im[2], im[3]);
    }
    __syncthreads();

    f32x4 acc[2][4];
#pragma unroll
    for (int mi = 0; mi < 2; ++mi)
#pragma unroll
        for (int nt = 0; nt < 4; ++nt) acc[mi][nt] = (f32x4)(0.0f);

    const short* A_hi = Apack + 65536;
    const short* A_lo = Apack + 65536 + 32768;

#pragma unroll 2
    for (int kc = 0; kc < 8; ++kc) {
        short8v bh[4];
#pragma unroll
        for (int nt = 0; nt < 4; ++nt)
            bh[nt] = *reinterpret_cast<const short8v*>(&Bs[kc][nt][lane][0]);
#pragma unroll
        for (int mi = 0; mi < 2; ++mi) {
            const int m = wv*2 + mi;
            const size_t off = (size_t)((m*8 + kc)*64 + lane)*8;
            const short8v arh = *reinterpret_cast<const short8v*>(A_hi + off);
            const short8v arl = *reinterpret_cast<const short8v*>(A_lo + off);
#pragma unroll
            for (int nt = 0; nt < 4; ++nt) {
                acc[mi][nt] = __builtin_amdgcn_mfma_f32_16x16x32_bf16(arh, bh[nt], acc[mi][nt], 0, 0, 0);
                acc[mi][nt] = __builtin_amdgcn_mfma_f32_16x16x32_bf16(arl, bh[nt], acc[mi][nt], 0, 0, 0);
            }
        }
    }

    const int col   = lane & 15;
    const int rbase = (lane >> 4) * 4;
    float lns = 0.f, lnq = 0.f;
#pragma unroll
    for (int mi = 0; mi < 2; ++mi) {
#pragma unroll
        for (int r = 0; r < 4; ++r) {
            const int o = wv*32 + mi*16 + rbase + r;
            const float br = bre[o];
#pragma unroll
            for (int nt = 0; nt < 4; ++nt) {
                const int wcol = nt*16 + col;
                const float v = acc[mi][nt][r] + br;
                outr[(size_t)bl*CHW + (size_t)o*HW + tt*64 + wcol] = f2bf(v);
                lns += v; lnq += v*v;
            }
        }
    }
#pragma unroll
    for (int off = 32; off > 0; off >>= 1) {
        lns += __shfl_down(lns, off);
        lnq += __shfl_down(lnq, off);
    }
    __shared__ float2 red[4];
    if (lane == 0) red[wv] = make_float2(lns, lnq);
    __syncthreads();
    if (t == 0) {
        float2 a = red[0], b2 = red[1], c2 = red[2], d = red[3];
        lnpart[bx] = make_float2(a.x + b2.x + c2.x + d.x, a.y + b2.y + c2.y + d.y);
    }
}

// ======================= LN apply with folded finish (verified r17 fallback) ======
__global__ __launch_bounds__(256) void ln_apply2_kernel(
    float* __restrict__ out0, const unsigned short* __restrict__ hpre,
    const float* __restrict__ x,
    const float* __restrict__ lnw, const float* __restrict__ lnb,
    const float2* __restrict__ lnpart)
{
    const int idx4 = blockIdx.x*256 + threadIdx.x;   // 4 elems per thread
    const int i = idx4 * 4;
    const int bl = i >> 17;                          // whole block shares one bl
    __shared__ float2 mstat;
    const int t = threadIdx.x;
    if (t < 64) {
        float s = 0.f, sq = 0.f;
        if (t < 16) { float2 v = lnpart[bl*16 + t]; s = v.x; sq = v.y; }
#pragma unroll
        for (int off = 8; off > 0; off >>= 1) {
            s  += __shfl_down(s, off);
            sq += __shfl_down(sq, off);
        }
        if (t == 0) {
            const float invN = 1.0f / (float)CHW;
            const float mean = s * invN;
            const float var  = sq * invN - mean*mean;
            mstat = make_float2(mean, rsqrtf(var + 1e-5f));
        }
    }
    __syncthreads();
    const float m = mstat.x, rs = mstat.y;

    const int chw4 = (i & (CHW - 1)) >> 2;
    const uint2 hu = reinterpret_cast<const uint2*>(hpre)[idx4];
    float4 h;
    h.x = __uint_as_float(hu.x << 16);
    h.y = __uint_as_float(hu.x & 0xFFFF0000u);
    h.z = __uint_as_float(hu.y << 16);
    h.w = __uint_as_float(hu.y & 0xFFFF0000u);
    float4 xv = reinterpret_cast<const float4*>(x)[idx4];
    float4 w  = reinterpret_cast<const float4*>(lnw)[chw4];
    float4 bb = reinterpret_cast<const float4*>(lnb)[chw4];
    float4 r;
    r.x = fmaf((h.x - m)*rs, w.x, bb.x) + xv.x;
    r.y = fmaf((h.y - m)*rs, w.y, bb.y) + xv.y;
    r.z = fmaf((h.z - m)*rs, w.z, bb.z) + xv.z;
    r.w = fmaf((h.w - m)*rs, w.w, bb.w) + xv.w;
    reinterpret_cast<float4*>(out0)[idx4] = r;
}

// ======================= launch =======================
extern "C" void kernel_launch(void* const* d_in, const int* in_sizes, int n_in,
                              void* d_out, int out_size, void* d_ws, size_t ws_size,
                              hipStream_t stream)
{
    const float* x     = (const float*)d_in[0];
    const float* pl    = (const float*)d_in[1];
    const float* Wb_re = (const float*)d_in[2];
    const float* Wb_im = (const float*)d_in[3];
    const float* bb_re = (const float*)d_in[4];
    const float* bb_im = (const float*)d_in[5];
    const float* Wc_re = (const float*)d_in[6];
    const float* Wc_im = (const float*)d_in[7];
    const float* bc_re = (const float*)d_in[8];
    const float* bc_im = (const float*)d_in[9];
    const float* ln_w  = (const float*)d_in[10];
    const float* ln_b  = (const float*)d_in[11];
    (void)bc_im;

    float* out0 = (float*)d_out;
    float* out1 = out0 + OUT0_ELEMS;

    char* ws = (char*)d_ws;
    unsigned*       bufA    = (unsigned*)       ws;                        // 33,554,432
    unsigned*       bufB    = (unsigned*)       (ws + 33554432);           // 33,554,432
    unsigned short* out0pre = (unsigned short*) (ws + 67108864);           // 16,777,216
    short*          Apack   = (short*)          (ws + 83886080);           //    262,144
    float*          gtab    = (float*)          (ws + 84148224);           //     16,384
    float2*         lnpart  = (float2*)         (ws + 84164608);           //      8,192

    const bool interleaved = ((size_t)out_size >= OUT0_ELEMS + 2*OUT1_CPLX);

    pack_w_kernel<<<48, 256, 0, stream>>>(Wb_re, Wb_im, Wc_re, Wc_im, pl, Apack, gtab);
    mix0_spatial_kernel<<<1024, 256, 0, stream>>>(x, bufA, Apack);
    fft_gamma_kernel<<<1024, 256, 0, stream>>>(bufA, bufB, gtab, bb_re, bb_im);
    if (interleaved)
        scan_fftw_kernel<1><<<1024, 256, 0, stream>>>(bufB, pl, out1);
    else
        scan_fftw_kernel<0><<<1024, 256, 0, stream>>>(bufB, pl, out1);
    ifft_h_bf_kernel<<<1024, 256, 0, stream>>>(bufB, bufA);
    mix1_kernel<<<1024, 256, 0, stream>>>(bufA, Apack, bc_re, out0pre, lnpart);
    ln_apply2_kernel<<<8192, 256, 0, stream>>>(out0, out0pre, x, ln_w, ln_b, lnpart);
}